// Round 10
// baseline (215.000 us; speedup 1.0000x reference)
//
#include <hip/hip_runtime.h>
#include <hip/hip_bf16.h>
#include <stdint.h>

#define B_ROWS 1024
#define DIM    512
#define C_CLS  100000
#define C_PAD  100352          // 8 XCDs * 49 ntiles * 256
#define NT     392             // C_PAD / 256
#define NT_PER_XCD 49
#define MT     4               // B_ROWS / 256
#define NPAD   (C_PAD - C_CLS) // 352 pad cols, logit 0

using f32x4  = __attribute__((ext_vector_type(4))) float;
using bf16x8 = __attribute__((ext_vector_type(8))) short;   // 8 bf16 (4 VGPRs)

#define AS1(p) ((const __attribute__((address_space(1))) uint32_t*)(p))
#define AS3(p) ((__attribute__((address_space(3))) uint32_t*)(p))
#define SBAR()   __builtin_amdgcn_s_barrier()
#define SCHED0() __builtin_amdgcn_sched_barrier(0)
#define PRIO1()  __builtin_amdgcn_s_setprio(1)
#define PRIO0()  __builtin_amdgcn_s_setprio(0)
#define VMCNT0() asm volatile("s_waitcnt vmcnt(0)" ::: "memory")

static __device__ __forceinline__ float bf2f(uint32_t u) { return __uint_as_float(u << 16); }
static __device__ __forceinline__ uint32_t f2bf(float f) {
    uint32_t u = __float_as_uint(f);
    u += 0x7fffu + ((u >> 16) & 1u);          // round-to-nearest-even
    return u >> 16;
}

// ---------- pass 1: per-row L2 normalize (one wave per row), f32 -> bf16; pad rows zeroed
__global__ __launch_bounds__(256) void normalize_rows(
    const float* __restrict__ src, uint16_t* __restrict__ dst, int nvalid, int ntotal)
{
    const int row  = blockIdx.x * 4 + (threadIdx.x >> 6);
    const int lane = threadIdx.x & 63;
    if (row >= ntotal) return;
    uint4* d4 = reinterpret_cast<uint4*>(dst + (size_t)row * DIM);
    if (row >= nvalid) { d4[lane] = make_uint4(0u, 0u, 0u, 0u); return; }
    const float4* s4 = reinterpret_cast<const float4*>(src + (size_t)row * DIM);
    const float4 a = s4[lane * 2], b = s4[lane * 2 + 1];
    float ss = a.x*a.x + a.y*a.y + a.z*a.z + a.w*a.w
             + b.x*b.x + b.y*b.y + b.z*b.z + b.w*b.w;
    #pragma unroll
    for (int k = 1; k < 64; k <<= 1) ss += __shfl_xor(ss, k);
    const float inv = 1.0f / fmaxf(sqrtf(ss), 1e-12f);
    uint4 o;
    o.x = f2bf(a.x*inv) | (f2bf(a.y*inv) << 16);
    o.y = f2bf(a.z*inv) | (f2bf(a.w*inv) << 16);
    o.z = f2bf(b.x*inv) | (f2bf(b.y*inv) << 16);
    o.w = f2bf(b.z*inv) | (f2bf(b.w*inv) << 16);
    d4[lane] = o;
}

// ---------- pass 2: 256x256 bf16 MFMA; SINGLE-buffered 64KiB LDS -> 2 blocks/CU;
//            cross-block TLP hides read/stage stalls (m114/m97 mechanism).
__global__ __launch_bounds__(512) void gemm_lse(
    const uint16_t* __restrict__ A,   // [B_ROWS][DIM]
    const uint16_t* __restrict__ W,   // [C_PAD][DIM]  (pad rows zero)
    float* __restrict__ ps)           // [NT][B_ROWS]
{
    // [region h: 0=A0(rows0-127), 1=A1, 2=B0(cols0-127), 3=B1][128*64 bf16], 64 KiB
    __shared__ __align__(16) uint16_t lds[4][128 * 64];

    const int tid  = threadIdx.x;
    const int lane = tid & 63;
    const int wid  = tid >> 6;       // 8 waves: 2M x 4N
    const int wr   = wid >> 2;       // 0..1  (128 rows each)
    const int wc   = wid & 3;        // 0..3  (64 cols each)

    const int b     = blockIdx.x;
    const int xcd   = b & 7;
    const int j     = b >> 3;        // 0..195 within XCD
    const int ntile = xcd * NT_PER_XCD + (j >> 2);
    const int mtile = j & 3;

    const uint16_t* Abase = A + (size_t)mtile * 256 * DIM;
    const uint16_t* Bbase = W + (size_t)ntile * 256 * DIM;

    // staging: region = 128 rows x 64 k = 16KB; 2 gload_lds(16B)/thread/region
    const int r0 = tid >> 3;
    const int us = (tid & 7) ^ (r0 & 7);      // pre-swizzled source unit (rule #21)
    const int r1 = r0 + 64;

    auto stage = [&](int kt, int h) {
        const uint16_t* src = ((h < 2) ? Abase : Bbase)
                            + (size_t)((h & 1) * 128) * DIM + kt * 64;
        uint16_t* dst = &lds[h][0];
        __builtin_amdgcn_global_load_lds(AS1(src + (size_t)r0 * DIM + us * 8),
                                         AS3(dst + tid * 8), 16, 0, 0);
        __builtin_amdgcn_global_load_lds(AS1(src + (size_t)r1 * DIM + us * 8),
                                         AS3(dst + (tid + 512) * 8), 16, 0, 0);
    };
    auto stage4 = [&](int kt) { stage(kt,0); stage(kt,1); stage(kt,2); stage(kt,3); };

    const int l15 = lane & 15;
    const int uhi = lane >> 4;
    const int ux  = lane & 7;

    bf16x8 aF[4][2], bF01[2][2], bF23[2][2];   // aF time-shared: rows 0-3 then 4-7
    f32x4 acc[8][4] = {};

    auto ldA = [&](int mi, int ks) {
        const int row  = mi * 16 + l15;
        const int unit = ((ks << 2) | uhi) ^ ux;
        return *reinterpret_cast<const bf16x8*>(&lds[wr][row * 64 + unit * 8]);
    };
    auto ldB = [&](int ni, int ks) {
        const int row  = (wc & 1) * 64 + ni * 16 + l15;
        const int unit = ((ks << 2) | uhi) ^ ux;
        return *reinterpret_cast<const bf16x8*>(&lds[2 + (wc >> 1)][row * 64 + unit * 8]);
    };
    auto rdA03 = [&]() {
        #pragma unroll
        for (int mi = 0; mi < 4; ++mi) { aF[mi][0] = ldA(mi, 0); aF[mi][1] = ldA(mi, 1); }
    };
    auto rdA47 = [&]() {
        #pragma unroll
        for (int mi = 0; mi < 4; ++mi) { aF[mi][0] = ldA(mi + 4, 0); aF[mi][1] = ldA(mi + 4, 1); }
    };
    auto rdB01 = [&]() {
        #pragma unroll
        for (int ni = 0; ni < 2; ++ni) { bF01[ni][0] = ldB(ni, 0); bF01[ni][1] = ldB(ni, 1); }
    };
    auto rdB23 = [&]() {
        #pragma unroll
        for (int ni = 0; ni < 2; ++ni) { bF23[ni][0] = ldB(ni + 2, 0); bF23[ni][1] = ldB(ni + 2, 1); }
    };

#define QUAD(BF, MH, NH) { PRIO1(); \
    _Pragma("unroll") for (int m2 = 0; m2 < 4; ++m2) \
    _Pragma("unroll") for (int n2 = 0; n2 < 2; ++n2) \
    _Pragma("unroll") for (int ks = 0; ks < 2; ++ks) \
        acc[(MH)*4+m2][(NH)*2+n2] = __builtin_amdgcn_mfma_f32_16x16x32_bf16( \
            aF[m2][ks], BF[n2][ks], acc[(MH)*4+m2][(NH)*2+n2], 0, 0, 0); \
    PRIO0(); }

    // prologue
    stage4(0);
    VMCNT0(); SBAR();

    #pragma unroll 1
    for (int kt = 0; kt < 8; ++kt) {
        // compute kt: reads issued just-in-time; compiler emits per-operand lgkmcnt.
        rdB01(); rdA03();
        QUAD(bF01, 0, 0); SCHED0();
        rdB23();
        QUAD(bF23, 0, 1); SCHED0();
        rdA47();
        QUAD(bF01, 1, 0); SCHED0();
        QUAD(bF23, 1, 1); SCHED0();
        SBAR();                        // every wave consumed (auto-waited) all its reads
        if (kt < 7) {
            stage4(kt + 1);            // safe: reads of kt certified done block-wide
            VMCNT0(); SCHED0();
            SBAR();                    // new tile landed for everyone
        }
    }

    // epilogue: logits = 64*cos in [-64,64]; fixed shift 64 -> sum exp(logit-64)
    __syncthreads();                               // full drain; reuse LDS as red buffer
    float* red = reinterpret_cast<float*>(&lds[0][0]);      // [256 rows][4 wc]
    #pragma unroll
    for (int mi = 0; mi < 8; ++mi) {
        #pragma unroll
        for (int r = 0; r < 4; ++r) {
            float s = __expf(fmaf(acc[mi][0][r], 64.0f, -64.0f))
                    + __expf(fmaf(acc[mi][1][r], 64.0f, -64.0f))
                    + __expf(fmaf(acc[mi][2][r], 64.0f, -64.0f))
                    + __expf(fmaf(acc[mi][3][r], 64.0f, -64.0f));
            #pragma unroll
            for (int k = 1; k < 16; k <<= 1) s += __shfl_xor(s, k);
            if (l15 == 0) red[(wr * 128 + mi * 16 + uhi * 4 + r) * 4 + wc] = s;
        }
    }
    __syncthreads();
    if (tid < 256)
        ps[(size_t)ntile * B_ROWS + mtile * 256 + tid] =
            red[tid*4+0] + red[tid*4+1] + red[tid*4+2] + red[tid*4+3];
}

// ---------- pass 3: per-row sum of partials + exact margin/pad correction
__global__ __launch_bounds__(256) void finalize(
    const float* __restrict__ ps,
    const uint16_t* __restrict__ fb, const uint16_t* __restrict__ wb,
    const int* __restrict__ labels, float* __restrict__ row_loss)
{
    const int row = blockIdx.x;
    const int t   = threadIdx.x;      // 256
    const int lab = labels[row];

    // target cosine in f32 from the same bf16 vectors the GEMM used
    uint32_t fa = reinterpret_cast<const uint32_t*>(fb + (size_t)row * DIM)[t];
    uint32_t wa = reinterpret_cast<const uint32_t*>(wb + (size_t)lab * DIM)[t];
    float d = bf2f(fa & 0xffffu) * bf2f(wa & 0xffffu) + bf2f(fa >> 16) * bf2f(wa >> 16);
    #pragma unroll
    for (int k = 1; k < 64; k <<= 1) d += __shfl_xor(d, k);

    float s = 0.0f;
    for (int i = t; i < NT; i += 256) s += ps[(size_t)i * B_ROWS + row];
    #pragma unroll
    for (int k = 1; k < 64; k <<= 1) s += __shfl_xor(s, k);

    __shared__ float sd[4], ssm[4];
    if ((t & 63) == 0) { sd[t >> 6] = d; ssm[t >> 6] = s; }
    __syncthreads();
    if (t == 0) {
        const float dt = sd[0] + sd[1] + sd[2] + sd[3];
        float S = ssm[0] + ssm[1] + ssm[2] + ssm[3];
        const float lt = 64.0f * dt;
        // swap unmargined target term for margined one; remove pad columns (logit 0)
        S += expf(lt - 96.0f) - expf(lt - 64.0f) - (float)NPAD * expf(-64.0f);
        row_loss[row] = 64.0f + logf(S) - (lt - 32.0f);
    }
}

// ---------- pass 4: mean over rows
__global__ __launch_bounds__(256) void mean_k(const float* __restrict__ rl, float* __restrict__ out)
{
    const int t = threadIdx.x;
    float s = 0.0f;
    for (int i = t; i < B_ROWS; i += 256) s += rl[i];
    #pragma unroll
    for (int k = 1; k < 64; k <<= 1) s += __shfl_xor(s, k);
    __shared__ float r4[4];
    if ((t & 63) == 0) r4[t >> 6] = s;
    __syncthreads();
    if (t == 0) out[0] = (r4[0] + r4[1] + r4[2] + r4[3]) * (1.0f / B_ROWS);
}

extern "C" void kernel_launch(void* const* d_in, const int* in_sizes, int n_in,
                              void* d_out, int out_size, void* d_ws, size_t ws_size,
                              hipStream_t stream)
{
    const float* features = (const float*)d_in[0];
    const int*   labels   = (const int*)d_in[1];
    const float* weight   = (const float*)d_in[2];

    char* ws = (char*)d_ws;
    uint16_t* wb = (uint16_t*)ws;                                        // C_PAD * DIM bf16
    uint16_t* fb = (uint16_t*)(ws + (size_t)C_PAD * DIM * 2);            // B_ROWS * DIM bf16
    float*    psum = (float*)(ws + (size_t)C_PAD * DIM * 2 + (size_t)B_ROWS * DIM * 2);
    float*    rl = psum + (size_t)NT * B_ROWS;

    normalize_rows<<<C_PAD / 4, 256, 0, stream>>>(weight, wb, C_CLS, C_PAD);
    normalize_rows<<<B_ROWS / 4, 256, 0, stream>>>(features, fb, B_ROWS, B_ROWS);
    gemm_lse<<<NT * MT, 512, 0, stream>>>(fb, wb, psum);
    finalize<<<B_ROWS, 256, 0, stream>>>(psum, fb, wb, labels, rl);
    mean_k<<<1, 256, 0, stream>>>(rl, (float*)d_out);
}

// Round 11
// 188.980 us; speedup vs baseline: 1.1377x; 1.1377x over previous
//
#include <hip/hip_runtime.h>
#include <hip/hip_bf16.h>
#include <stdint.h>

#define B_ROWS 1024
#define DIM    512
#define C_CLS  100000
#define C_PAD  100352          // 8 XCDs * 49 ntiles * 256
#define NT     392             // C_PAD / 256
#define NT_PER_XCD 49
#define MT     4               // B_ROWS / 256
#define NPAD   (C_PAD - C_CLS) // 352 pad cols, logit 0

using f32x4  = __attribute__((ext_vector_type(4))) float;
using bf16x8 = __attribute__((ext_vector_type(8))) short;   // 8 bf16 (4 VGPRs)

#define AS1(p) ((const __attribute__((address_space(1))) uint32_t*)(p))
#define AS3(p) ((__attribute__((address_space(3))) uint32_t*)(p))
#define SBAR()   __builtin_amdgcn_s_barrier()
#define SCHED0() __builtin_amdgcn_sched_barrier(0)
#define VMCNT0() asm volatile("s_waitcnt vmcnt(0)" ::: "memory")

static __device__ __forceinline__ float bf2f(uint32_t u) { return __uint_as_float(u << 16); }
static __device__ __forceinline__ uint32_t f2bf(float f) {
    uint32_t u = __float_as_uint(f);
    u += 0x7fffu + ((u >> 16) & 1u);          // round-to-nearest-even
    return u >> 16;
}

// ---------- pass 1: per-row L2 normalize (one wave per row), f32 -> bf16; pad rows zeroed
__global__ __launch_bounds__(256) void normalize_rows(
    const float* __restrict__ src, uint16_t* __restrict__ dst, int nvalid, int ntotal)
{
    const int row  = blockIdx.x * 4 + (threadIdx.x >> 6);
    const int lane = threadIdx.x & 63;
    if (row >= ntotal) return;
    uint4* d4 = reinterpret_cast<uint4*>(dst + (size_t)row * DIM);
    if (row >= nvalid) { d4[lane] = make_uint4(0u, 0u, 0u, 0u); return; }
    const float4* s4 = reinterpret_cast<const float4*>(src + (size_t)row * DIM);
    const float4 a = s4[lane * 2], b = s4[lane * 2 + 1];
    float ss = a.x*a.x + a.y*a.y + a.z*a.z + a.w*a.w
             + b.x*b.x + b.y*b.y + b.z*b.z + b.w*b.w;
    #pragma unroll
    for (int k = 1; k < 64; k <<= 1) ss += __shfl_xor(ss, k);
    const float inv = 1.0f / fmaxf(sqrtf(ss), 1e-12f);
    uint4 o;
    o.x = f2bf(a.x*inv) | (f2bf(a.y*inv) << 16);
    o.y = f2bf(a.z*inv) | (f2bf(a.w*inv) << 16);
    o.z = f2bf(b.x*inv) | (f2bf(b.y*inv) << 16);
    o.w = f2bf(b.z*inv) | (f2bf(b.w*inv) << 16);
    d4[lane] = o;
}

// ---------- pass 2: 256x256 bf16 MFMA; dbuf + JIT per-quad reads, compiler-scheduled
//            interleave (auto per-register lgkmcnt), ONE vmcnt0+barrier per K-tile.
__global__ __launch_bounds__(512) void gemm_lse(
    const uint16_t* __restrict__ A,   // [B_ROWS][DIM]
    const uint16_t* __restrict__ W,   // [C_PAD][DIM]  (pad rows zero)
    float* __restrict__ ps)           // [NT][B_ROWS]
{
    // [buf][region h: 0=A0(rows0-127), 1=A1, 2=B0(cols0-127), 3=B1][128*64 bf16], 128 KiB
    __shared__ __align__(16) uint16_t lds[2][4][128 * 64];

    const int tid  = threadIdx.x;
    const int lane = tid & 63;
    const int wid  = tid >> 6;       // 8 waves: 2M x 4N
    const int wr   = wid >> 2;       // 0..1  (128 rows each)
    const int wc   = wid & 3;        // 0..3  (64 cols each)

    const int b     = blockIdx.x;
    const int xcd   = b & 7;
    const int j     = b >> 3;        // 0..195 within XCD
    const int ntile = xcd * NT_PER_XCD + (j >> 2);
    const int mtile = j & 3;

    const uint16_t* Abase = A + (size_t)mtile * 256 * DIM;
    const uint16_t* Bbase = W + (size_t)ntile * 256 * DIM;

    // staging: half-tile = 128 rows x 64 k = 16KB; 2 gload_lds(16B)/thread/region
    const int r0 = tid >> 3;
    const int us = (tid & 7) ^ (r0 & 7);      // pre-swizzled source unit (rule #21)
    const int r1 = r0 + 64;

    auto stage = [&](int kt, int h) {
        const uint16_t* src = ((h < 2) ? Abase : Bbase)
                            + (size_t)((h & 1) * 128) * DIM + kt * 64;
        uint16_t* dst = &lds[kt & 1][h][0];
        __builtin_amdgcn_global_load_lds(AS1(src + (size_t)r0 * DIM + us * 8),
                                         AS3(dst + tid * 8), 16, 0, 0);
        __builtin_amdgcn_global_load_lds(AS1(src + (size_t)r1 * DIM + us * 8),
                                         AS3(dst + (tid + 512) * 8), 16, 0, 0);
    };
    auto stage4 = [&](int kt) { stage(kt,0); stage(kt,1); stage(kt,2); stage(kt,3); };

    const int l15 = lane & 15;
    const int uhi = lane >> 4;
    const int ux  = lane & 7;

    bf16x8 aF[4][2], bF01[2][2], bF23[2][2];   // aF time-shared: rows 0-3 then 4-7
    f32x4 acc[8][4] = {};

    auto ldA = [&](int buf, int mi, int ks) {
        const int row  = mi * 16 + l15;
        const int unit = ((ks << 2) | uhi) ^ ux;
        return *reinterpret_cast<const bf16x8*>(&lds[buf][wr][row * 64 + unit * 8]);
    };
    auto ldB = [&](int buf, int ni, int ks) {
        const int row  = (wc & 1) * 64 + ni * 16 + l15;
        const int unit = ((ks << 2) | uhi) ^ ux;
        return *reinterpret_cast<const bf16x8*>(&lds[buf][2 + (wc >> 1)][row * 64 + unit * 8]);
    };
    auto rdA03 = [&](int buf) {
        #pragma unroll
        for (int mi = 0; mi < 4; ++mi) { aF[mi][0] = ldA(buf, mi, 0); aF[mi][1] = ldA(buf, mi, 1); }
    };
    auto rdA47 = [&](int buf) {
        #pragma unroll
        for (int mi = 0; mi < 4; ++mi) { aF[mi][0] = ldA(buf, mi + 4, 0); aF[mi][1] = ldA(buf, mi + 4, 1); }
    };
    auto rdB01 = [&](int buf) {
        #pragma unroll
        for (int ni = 0; ni < 2; ++ni) { bF01[ni][0] = ldB(buf, ni, 0); bF01[ni][1] = ldB(buf, ni, 1); }
    };
    auto rdB23 = [&](int buf) {
        #pragma unroll
        for (int ni = 0; ni < 2; ++ni) { bF23[ni][0] = ldB(buf, ni + 2, 0); bF23[ni][1] = ldB(buf, ni + 2, 1); }
    };

// ks OUTER: 8 consecutive independent MFMAs (dep distance 8 on acc), no latency stalls
#define QUAD(BF, MH, NH) { \
    _Pragma("unroll") for (int ks = 0; ks < 2; ++ks) \
    _Pragma("unroll") for (int m2 = 0; m2 < 4; ++m2) \
    _Pragma("unroll") for (int n2 = 0; n2 < 2; ++n2) \
        acc[(MH)*4+m2][(NH)*2+n2] = __builtin_amdgcn_mfma_f32_16x16x32_bf16( \
            aF[m2][ks], BF[n2][ks], acc[(MH)*4+m2][(NH)*2+n2], 0, 0, 0); }

    // prologue
    stage4(0);
    VMCNT0(); SBAR(); SCHED0();

    #pragma unroll 1
    for (int kt = 0; kt < 8; ++kt) {
        const int cur = kt & 1;
        // JIT reads feed QUADs via compiler auto-lgkmcnt; later QUADs hide later reads.
        rdB01(cur); rdA03(cur);
        QUAD(bF01, 0, 0);
        rdB23(cur);
        if (kt < 7) stage4(kt + 1);      // issue early: lands ~1 K-tile before VMCNT0
        QUAD(bF23, 0, 1);
        rdA47(cur);
        QUAD(bF01, 1, 0);
        QUAD(bF23, 1, 1);
        VMCNT0();                        // near-free: stage issued ~1500 cy ago (L2-hit)
        SBAR(); SCHED0();                // next tile certified for all waves
    }

    // epilogue: logits = 64*cos in [-64,64]; fixed shift 64 -> sum exp(logit-64)
    __syncthreads();                               // full drain; reuse LDS as red buffer
    float* red = reinterpret_cast<float*>(&lds[0][0][0]);   // [256 rows][4 wc]
    #pragma unroll
    for (int mi = 0; mi < 8; ++mi) {
        #pragma unroll
        for (int r = 0; r < 4; ++r) {
            float s = __expf(fmaf(acc[mi][0][r], 64.0f, -64.0f))
                    + __expf(fmaf(acc[mi][1][r], 64.0f, -64.0f))
                    + __expf(fmaf(acc[mi][2][r], 64.0f, -64.0f))
                    + __expf(fmaf(acc[mi][3][r], 64.0f, -64.0f));
            #pragma unroll
            for (int k = 1; k < 16; k <<= 1) s += __shfl_xor(s, k);
            if (l15 == 0) red[(wr * 128 + mi * 16 + uhi * 4 + r) * 4 + wc] = s;
        }
    }
    __syncthreads();
    if (tid < 256)
        ps[(size_t)ntile * B_ROWS + mtile * 256 + tid] =
            red[tid*4+0] + red[tid*4+1] + red[tid*4+2] + red[tid*4+3];
}

// ---------- pass 3: per-row sum of partials + exact margin/pad correction
__global__ __launch_bounds__(256) void finalize(
    const float* __restrict__ ps,
    const uint16_t* __restrict__ fb, const uint16_t* __restrict__ wb,
    const int* __restrict__ labels, float* __restrict__ row_loss)
{
    const int row = blockIdx.x;
    const int t   = threadIdx.x;      // 256
    const int lab = labels[row];

    // target cosine in f32 from the same bf16 vectors the GEMM used
    uint32_t fa = reinterpret_cast<const uint32_t*>(fb + (size_t)row * DIM)[t];
    uint32_t wa = reinterpret_cast<const uint32_t*>(wb + (size_t)lab * DIM)[t];
    float d = bf2f(fa & 0xffffu) * bf2f(wa & 0xffffu) + bf2f(fa >> 16) * bf2f(wa >> 16);
    #pragma unroll
    for (int k = 1; k < 64; k <<= 1) d += __shfl_xor(d, k);

    float s = 0.0f;
    for (int i = t; i < NT; i += 256) s += ps[(size_t)i * B_ROWS + row];
    #pragma unroll
    for (int k = 1; k < 64; k <<= 1) s += __shfl_xor(s, k);

    __shared__ float sd[4], ssm[4];
    if ((t & 63) == 0) { sd[t >> 6] = d; ssm[t >> 6] = s; }
    __syncthreads();
    if (t == 0) {
        const float dt = sd[0] + sd[1] + sd[2] + sd[3];
        float S = ssm[0] + ssm[1] + ssm[2] + ssm[3];
        const float lt = 64.0f * dt;
        // swap unmargined target term for margined one; remove pad columns (logit 0)
        S += expf(lt - 96.0f) - expf(lt - 64.0f) - (float)NPAD * expf(-64.0f);
        row_loss[row] = 64.0f + logf(S) - (lt - 32.0f);
    }
}

// ---------- pass 4: mean over rows
__global__ __launch_bounds__(256) void mean_k(const float* __restrict__ rl, float* __restrict__ out)
{
    const int t = threadIdx.x;
    float s = 0.0f;
    for (int i = t; i < B_ROWS; i += 256) s += rl[i];
    #pragma unroll
    for (int k = 1; k < 64; k <<= 1) s += __shfl_xor(s, k);
    __shared__ float r4[4];
    if ((t & 63) == 0) r4[t >> 6] = s;
    __syncthreads();
    if (t == 0) out[0] = (r4[0] + r4[1] + r4[2] + r4[3]) * (1.0f / B_ROWS);
}

extern "C" void kernel_launch(void* const* d_in, const int* in_sizes, int n_in,
                              void* d_out, int out_size, void* d_ws, size_t ws_size,
                              hipStream_t stream)
{
    const float* features = (const float*)d_in[0];
    const int*   labels   = (const int*)d_in[1];
    const float* weight   = (const float*)d_in[2];

    char* ws = (char*)d_ws;
    uint16_t* wb = (uint16_t*)ws;                                        // C_PAD * DIM bf16
    uint16_t* fb = (uint16_t*)(ws + (size_t)C_PAD * DIM * 2);            // B_ROWS * DIM bf16
    float*    psum = (float*)(ws + (size_t)C_PAD * DIM * 2 + (size_t)B_ROWS * DIM * 2);
    float*    rl = psum + (size_t)NT * B_ROWS;

    normalize_rows<<<C_PAD / 4, 256, 0, stream>>>(weight, wb, C_CLS, C_PAD);
    normalize_rows<<<B_ROWS / 4, 256, 0, stream>>>(features, fb, B_ROWS, B_ROWS);
    gemm_lse<<<NT * MT, 512, 0, stream>>>(fb, wb, psum);
    finalize<<<B_ROWS, 256, 0, stream>>>(psum, fb, wb, labels, rl);
    mean_k<<<1, 256, 0, stream>>>(rl, (float*)d_out);
}

// Round 12
// 176.609 us; speedup vs baseline: 1.2174x; 1.0700x over previous
//
#include <hip/hip_runtime.h>
#include <hip/hip_bf16.h>
#include <stdint.h>

#define B_ROWS 1024
#define DIM    512
#define C_CLS  100000
#define C_PAD  100352          // 8 XCDs * 98 ntiles * 128
#define NT     784             // C_PAD / 128
#define NT_PER_XCD 98
#define MT     8               // B_ROWS / 128
#define NPAD   (C_PAD - C_CLS) // 352 pad cols, logit 0

using f32x4  = __attribute__((ext_vector_type(4))) float;
using bf16x8 = __attribute__((ext_vector_type(8))) short;   // 8 bf16 (4 VGPRs)

#define AS1(p) ((const __attribute__((address_space(1))) uint32_t*)(p))
#define AS3(p) ((__attribute__((address_space(3))) uint32_t*)(p))
#define SBAR()   __builtin_amdgcn_s_barrier()
#define VMCNT0() asm volatile("s_waitcnt vmcnt(0)" ::: "memory")

static __device__ __forceinline__ float bf2f(uint32_t u) { return __uint_as_float(u << 16); }
static __device__ __forceinline__ uint32_t f2bf(float f) {
    uint32_t u = __float_as_uint(f);
    u += 0x7fffu + ((u >> 16) & 1u);          // round-to-nearest-even
    return u >> 16;
}

// ---------- pass 1: per-row L2 normalize (one wave per row), f32 -> bf16; pad rows zeroed
__global__ __launch_bounds__(256) void normalize_rows(
    const float* __restrict__ src, uint16_t* __restrict__ dst, int nvalid, int ntotal)
{
    const int row  = blockIdx.x * 4 + (threadIdx.x >> 6);
    const int lane = threadIdx.x & 63;
    if (row >= ntotal) return;
    uint4* d4 = reinterpret_cast<uint4*>(dst + (size_t)row * DIM);
    if (row >= nvalid) { d4[lane] = make_uint4(0u, 0u, 0u, 0u); return; }
    const float4* s4 = reinterpret_cast<const float4*>(src + (size_t)row * DIM);
    const float4 a = s4[lane * 2], b = s4[lane * 2 + 1];
    float ss = a.x*a.x + a.y*a.y + a.z*a.z + a.w*a.w
             + b.x*b.x + b.y*b.y + b.z*b.z + b.w*b.w;
    #pragma unroll
    for (int k = 1; k < 64; k <<= 1) ss += __shfl_xor(ss, k);
    const float inv = 1.0f / fmaxf(sqrtf(ss), 1e-12f);
    uint4 o;
    o.x = f2bf(a.x*inv) | (f2bf(a.y*inv) << 16);
    o.y = f2bf(a.z*inv) | (f2bf(a.w*inv) << 16);
    o.z = f2bf(b.x*inv) | (f2bf(b.y*inv) << 16);
    o.w = f2bf(b.z*inv) | (f2bf(b.w*inv) << 16);
    d4[lane] = o;
}

// ---------- pass 2: 128x128 bf16 MFMA, m97 structure: 4 waves, single 32KiB LDS buffer,
//            3 blocks/CU -> cross-block TLP hides stage drains and LDS read bursts.
__global__ __launch_bounds__(256, 3) void gemm_lse(
    const uint16_t* __restrict__ A,   // [B_ROWS][DIM]
    const uint16_t* __restrict__ W,   // [C_PAD][DIM]  (pad rows zero)
    float* __restrict__ ps)           // [NT][B_ROWS]
{
    // [region: 0=A, 1=B][128 rows * 64 k bf16], 32 KiB single buffer
    __shared__ __align__(16) uint16_t lds[2][128 * 64];

    const int tid  = threadIdx.x;
    const int lane = tid & 63;
    const int wid  = tid >> 6;       // 4 waves, 2x2: each owns 64x64
    const int wm   = wid >> 1;
    const int wn   = wid & 1;

    const int b     = blockIdx.x;
    const int xcd   = b & 7;
    const int j     = b >> 3;        // 0..783 within XCD
    const int ntile = xcd * NT_PER_XCD + (j >> 3);
    const int mtile = j & 7;

    const uint16_t* Abase = A + (size_t)mtile * 128 * DIM;
    const uint16_t* Bbase = W + (size_t)ntile * 128 * DIM;

    // staging: per region 16 chunks of 8 rows; wave wid, iter c -> chunk = wid*4+c
    const int srow8 = lane >> 3;
    const int su    = (lane & 7) ^ srow8;     // pre-swizzled source unit (rule #21)

    auto stage = [&](int kt) {
        #pragma unroll
        for (int c = 0; c < 4; ++c) {
            const int chunk = wid * 4 + c;    // wave-uniform
            const int row   = chunk * 8 + srow8;
            __builtin_amdgcn_global_load_lds(
                AS1(Abase + (size_t)row * DIM + kt * 64 + su * 8),
                AS3(&lds[0][chunk * 512]), 16, 0, 0);
            __builtin_amdgcn_global_load_lds(
                AS1(Bbase + (size_t)row * DIM + kt * 64 + su * 8),
                AS3(&lds[1][chunk * 512]), 16, 0, 0);
        }
    };

    const int l15 = lane & 15;
    const int uhi = lane >> 4;
    const int ux  = lane & 7;

    bf16x8 aF[4][2], bF[4][2];
    f32x4 acc[4][4] = {};

    auto ldA = [&](int mi, int ks) {
        const int row  = wm * 64 + mi * 16 + l15;
        const int unit = ((ks << 2) | uhi) ^ ux;
        return *reinterpret_cast<const bf16x8*>(&lds[0][row * 64 + unit * 8]);
    };
    auto ldB = [&](int ni, int ks) {
        const int row  = wn * 64 + ni * 16 + l15;
        const int unit = ((ks << 2) | uhi) ^ ux;
        return *reinterpret_cast<const bf16x8*>(&lds[1][row * 64 + unit * 8]);
    };

    // prologue
    stage(0);

    #pragma unroll 1
    for (int kt = 0; kt < 8; ++kt) {
        VMCNT0(); SBAR();                 // tile kt landed for all waves
        #pragma unroll
        for (int mi = 0; mi < 4; ++mi) { aF[mi][0] = ldA(mi, 0); aF[mi][1] = ldA(mi, 1); }
        #pragma unroll
        for (int ni = 0; ni < 4; ++ni) { bF[ni][0] = ldB(ni, 0); bF[ni][1] = ldB(ni, 1); }
        #pragma unroll
        for (int ks = 0; ks < 2; ++ks)
            #pragma unroll
            for (int mi = 0; mi < 4; ++mi)
                #pragma unroll
                for (int ni = 0; ni < 4; ++ni)
                    acc[mi][ni] = __builtin_amdgcn_mfma_f32_16x16x32_bf16(
                        aF[mi][ks], bF[ni][ks], acc[mi][ni], 0, 0, 0);
        SBAR();                           // all waves' reads retired -> overwrite safe
        if (kt < 7) stage(kt + 1);
    }

    // epilogue: logits = 64*cos in [-64,64]; fixed shift 64 -> sum exp(logit-64)
    __syncthreads();                               // full drain; reuse LDS as red buffer
    float* red = reinterpret_cast<float*>(&lds[0][0]);      // [128 rows][2 wn]
    #pragma unroll
    for (int mi = 0; mi < 4; ++mi) {
        #pragma unroll
        for (int r = 0; r < 4; ++r) {
            float s = __expf(fmaf(acc[mi][0][r], 64.0f, -64.0f))
                    + __expf(fmaf(acc[mi][1][r], 64.0f, -64.0f))
                    + __expf(fmaf(acc[mi][2][r], 64.0f, -64.0f))
                    + __expf(fmaf(acc[mi][3][r], 64.0f, -64.0f));
            #pragma unroll
            for (int k = 1; k < 16; k <<= 1) s += __shfl_xor(s, k);
            if (l15 == 0) red[(wm * 64 + mi * 16 + uhi * 4 + r) * 2 + wn] = s;
        }
    }
    __syncthreads();
    if (tid < 128)
        ps[(size_t)ntile * B_ROWS + mtile * 128 + tid] = red[tid * 2] + red[tid * 2 + 1];
}

// ---------- pass 3: per-row sum of partials + exact margin/pad correction
__global__ __launch_bounds__(256) void finalize(
    const float* __restrict__ ps,
    const uint16_t* __restrict__ fb, const uint16_t* __restrict__ wb,
    const int* __restrict__ labels, float* __restrict__ row_loss)
{
    const int row = blockIdx.x;
    const int t   = threadIdx.x;      // 256
    const int lab = labels[row];

    // target cosine in f32 from the same bf16 vectors the GEMM used
    uint32_t fa = reinterpret_cast<const uint32_t*>(fb + (size_t)row * DIM)[t];
    uint32_t wa = reinterpret_cast<const uint32_t*>(wb + (size_t)lab * DIM)[t];
    float d = bf2f(fa & 0xffffu) * bf2f(wa & 0xffffu) + bf2f(fa >> 16) * bf2f(wa >> 16);
    #pragma unroll
    for (int k = 1; k < 64; k <<= 1) d += __shfl_xor(d, k);

    float s = 0.0f;
    for (int i = t; i < NT; i += 256) s += ps[(size_t)i * B_ROWS + row];
    #pragma unroll
    for (int k = 1; k < 64; k <<= 1) s += __shfl_xor(s, k);

    __shared__ float sd[4], ssm[4];
    if ((t & 63) == 0) { sd[t >> 6] = d; ssm[t >> 6] = s; }
    __syncthreads();
    if (t == 0) {
        const float dt = sd[0] + sd[1] + sd[2] + sd[3];
        float S = ssm[0] + ssm[1] + ssm[2] + ssm[3];
        const float lt = 64.0f * dt;
        // swap unmargined target term for margined one; remove pad columns (logit 0)
        S += expf(lt - 96.0f) - expf(lt - 64.0f) - (float)NPAD * expf(-64.0f);
        row_loss[row] = 64.0f + logf(S) - (lt - 32.0f);
    }
}

// ---------- pass 4: mean over rows
__global__ __launch_bounds__(256) void mean_k(const float* __restrict__ rl, float* __restrict__ out)
{
    const int t = threadIdx.x;
    float s = 0.0f;
    for (int i = t; i < B_ROWS; i += 256) s += rl[i];
    #pragma unroll
    for (int k = 1; k < 64; k <<= 1) s += __shfl_xor(s, k);
    __shared__ float r4[4];
    if ((t & 63) == 0) r4[t >> 6] = s;
    __syncthreads();
    if (t == 0) out[0] = (r4[0] + r4[1] + r4[2] + r4[3]) * (1.0f / B_ROWS);
}

extern "C" void kernel_launch(void* const* d_in, const int* in_sizes, int n_in,
                              void* d_out, int out_size, void* d_ws, size_t ws_size,
                              hipStream_t stream)
{
    const float* features = (const float*)d_in[0];
    const int*   labels   = (const int*)d_in[1];
    const float* weight   = (const float*)d_in[2];

    char* ws = (char*)d_ws;
    uint16_t* wb = (uint16_t*)ws;                                        // C_PAD * DIM bf16
    uint16_t* fb = (uint16_t*)(ws + (size_t)C_PAD * DIM * 2);            // B_ROWS * DIM bf16
    float*    psum = (float*)(ws + (size_t)C_PAD * DIM * 2 + (size_t)B_ROWS * DIM * 2);
    float*    rl = psum + (size_t)NT * B_ROWS;

    normalize_rows<<<C_PAD / 4, 256, 0, stream>>>(weight, wb, C_CLS, C_PAD);
    normalize_rows<<<B_ROWS / 4, 256, 0, stream>>>(features, fb, B_ROWS, B_ROWS);
    gemm_lse<<<NT * MT, 256, 0, stream>>>(fb, wb, psum);
    finalize<<<B_ROWS, 256, 0, stream>>>(psum, fb, wb, labels, rl);
    mean_k<<<1, 256, 0, stream>>>(rl, (float*)d_out);
}

// Round 13
// 136.748 us; speedup vs baseline: 1.5722x; 1.2915x over previous
//
#include <hip/hip_runtime.h>
#include <hip/hip_bf16.h>
#include <hip/hip_fp8.h>
#include <stdint.h>

#define B_ROWS 1024
#define DIM    512
#define C_CLS  100000
#define C_PAD  100352          // 8 XCDs * 98 ntiles * 128
#define NT     784             // C_PAD / 128
#define NT_PER_XCD 98
#define MT     8               // B_ROWS / 128
#define NPAD   (C_PAD - C_CLS) // 352 pad cols, logit 0

using f32x4  = __attribute__((ext_vector_type(4))) float;

#define AS1(p) ((const __attribute__((address_space(1))) uint32_t*)(p))
#define AS3(p) ((__attribute__((address_space(3))) uint32_t*)(p))
#define SBAR()   __builtin_amdgcn_s_barrier()
#define VMCNT0() asm volatile("s_waitcnt vmcnt(0)" ::: "memory")

static __device__ __forceinline__ uint32_t f2fp8(float f) {
    __hip_fp8_e4m3 q(f);
    return (uint32_t)q.__x;
}
static __device__ __forceinline__ float fp82f(uint32_t b) {
    __hip_fp8_e4m3 h;
    h.__x = (__hip_fp8_storage_t)b;
    return (float)h;
}

// ---------- pass 1: per-row L2 normalize (one wave per row), f32 -> fp8 e4m3; pad rows zeroed
__global__ __launch_bounds__(256) void normalize_rows(
    const float* __restrict__ src, uint8_t* __restrict__ dst, int nvalid, int ntotal)
{
    const int row  = blockIdx.x * 4 + (threadIdx.x >> 6);
    const int lane = threadIdx.x & 63;
    if (row >= ntotal) return;
    uint2* d2 = reinterpret_cast<uint2*>(dst + (size_t)row * DIM);    // 8 B per lane
    if (row >= nvalid) { d2[lane] = make_uint2(0u, 0u); return; }
    const float4* s4 = reinterpret_cast<const float4*>(src + (size_t)row * DIM);
    const float4 a = s4[lane * 2], b = s4[lane * 2 + 1];
    float ss = a.x*a.x + a.y*a.y + a.z*a.z + a.w*a.w
             + b.x*b.x + b.y*b.y + b.z*b.z + b.w*b.w;
    #pragma unroll
    for (int k = 1; k < 64; k <<= 1) ss += __shfl_xor(ss, k);
    const float inv = 1.0f / fmaxf(sqrtf(ss), 1e-12f);
    uint2 o;
    o.x = f2fp8(a.x*inv) | (f2fp8(a.y*inv) << 8) | (f2fp8(a.z*inv) << 16) | (f2fp8(a.w*inv) << 24);
    o.y = f2fp8(b.x*inv) | (f2fp8(b.y*inv) << 8) | (f2fp8(b.z*inv) << 16) | (f2fp8(b.w*inv) << 24);
    d2[lane] = o;
}

// ---------- pass 2: 128x128 fp8 MFMA, m97 structure: 4 waves, single 16KiB LDS buffer,
//            high TLP (3-4 blocks/CU); halved staging/LDS-read bytes vs bf16.
__global__ __launch_bounds__(256, 3) void gemm_lse(
    const uint8_t* __restrict__ A,    // [B_ROWS][DIM]  fp8
    const uint8_t* __restrict__ W,    // [C_PAD][DIM]   fp8 (pad rows zero)
    float* __restrict__ ps)           // [NT][B_ROWS]
{
    // [region: 0=A, 1=B][128 rows * 64 k fp8 = 8192 B], 16 KiB single buffer
    __shared__ __align__(16) uint8_t lds[2][128 * 64];

    const int tid  = threadIdx.x;
    const int lane = tid & 63;
    const int wid  = tid >> 6;       // 4 waves, 2x2: each owns 64x64
    const int wm   = wid >> 1;
    const int wn   = wid & 1;

    const int b     = blockIdx.x;
    const int xcd   = b & 7;
    const int j     = b >> 3;        // 0..783 within XCD
    const int ntile = xcd * NT_PER_XCD + (j >> 3);
    const int mtile = j & 7;

    const uint8_t* Abase = A + (size_t)mtile * 128 * DIM;
    const uint8_t* Bbase = W + (size_t)ntile * 128 * DIM;

    // staging: per region, thread t writes 16B units at t*16 and 4096+t*16
    //   unit u=t covers row u>>2, LDS 8B-subunits {(u&3)*2, +1}; source subunit
    //   = lds_subunit ^ (row & 6)  (even XOR keeps the 16B source contiguous).
    const int rr = tid >> 2;                                    // 0..63
    const int cc = ((((tid & 3) << 1) ^ (rr & 6)) << 3);        // byte col in 64

    auto stage = [&](int kt) {
        const uint8_t* As = Abase + (size_t)rr * DIM + kt * 64 + cc;
        const uint8_t* Bs = Bbase + (size_t)rr * DIM + kt * 64 + cc;
        __builtin_amdgcn_global_load_lds(AS1(As),            AS3(&lds[0][tid * 16]),        16, 0, 0);
        __builtin_amdgcn_global_load_lds(AS1(As + 64 * DIM), AS3(&lds[0][4096 + tid * 16]), 16, 0, 0);
        __builtin_amdgcn_global_load_lds(AS1(Bs),            AS3(&lds[1][tid * 16]),        16, 0, 0);
        __builtin_amdgcn_global_load_lds(AS1(Bs + 64 * DIM), AS3(&lds[1][4096 + tid * 16]), 16, 0, 0);
    };

    const int l15 = lane & 15;
    const int uhi = lane >> 4;       // k-quarter: lane holds k = uhi*8 .. +8

    long aF[4][2], bF[4][2];
    f32x4 acc[4][4] = {};

    auto ldA = [&](int mi, int ks) {
        const int row = wm * 64 + mi * 16 + l15;
        const int v   = ((ks << 2) | uhi) ^ (row & 6);          // swizzled 8B subunit
        return *reinterpret_cast<const long*>(&lds[0][row * 64 + v * 8]);
    };
    auto ldB = [&](int ni, int ks) {
        const int row = wn * 64 + ni * 16 + l15;
        const int v   = ((ks << 2) | uhi) ^ (row & 6);
        return *reinterpret_cast<const long*>(&lds[1][row * 64 + v * 8]);
    };

    // prologue
    stage(0);

    #pragma unroll 1
    for (int kt = 0; kt < 8; ++kt) {
        VMCNT0(); SBAR();                 // tile kt landed for all waves
        #pragma unroll
        for (int mi = 0; mi < 4; ++mi) { aF[mi][0] = ldA(mi, 0); aF[mi][1] = ldA(mi, 1); }
        #pragma unroll
        for (int ni = 0; ni < 4; ++ni) { bF[ni][0] = ldB(ni, 0); bF[ni][1] = ldB(ni, 1); }
        #pragma unroll
        for (int ks = 0; ks < 2; ++ks)
            #pragma unroll
            for (int mi = 0; mi < 4; ++mi)
                #pragma unroll
                for (int ni = 0; ni < 4; ++ni)
                    acc[mi][ni] = __builtin_amdgcn_mfma_f32_16x16x32_fp8_fp8(
                        aF[mi][ks], bF[ni][ks], acc[mi][ni], 0, 0, 0);
        SBAR();                           // all waves' reads retired -> overwrite safe
        if (kt < 7) stage(kt + 1);
    }

    // epilogue: logits = 64*cos in [-64,64]; fixed shift 64 -> sum exp(logit-64)
    __syncthreads();                               // full drain; reuse LDS as red buffer
    float* red = reinterpret_cast<float*>(&lds[0][0]);      // [128 rows][2 wn]
    #pragma unroll
    for (int mi = 0; mi < 4; ++mi) {
        #pragma unroll
        for (int r = 0; r < 4; ++r) {
            float s = __expf(fmaf(acc[mi][0][r], 64.0f, -64.0f))
                    + __expf(fmaf(acc[mi][1][r], 64.0f, -64.0f))
                    + __expf(fmaf(acc[mi][2][r], 64.0f, -64.0f))
                    + __expf(fmaf(acc[mi][3][r], 64.0f, -64.0f));
            #pragma unroll
            for (int k = 1; k < 16; k <<= 1) s += __shfl_xor(s, k);
            if (l15 == 0) red[(wm * 64 + mi * 16 + uhi * 4 + r) * 2 + wn] = s;
        }
    }
    __syncthreads();
    if (tid < 128)
        ps[(size_t)ntile * B_ROWS + mtile * 128 + tid] = red[tid * 2] + red[tid * 2 + 1];
}

// ---------- pass 3: per-row sum of partials + exact margin/pad correction
__global__ __launch_bounds__(256) void finalize(
    const float* __restrict__ ps,
    const uint8_t* __restrict__ fb, const uint8_t* __restrict__ wb,
    const int* __restrict__ labels, float* __restrict__ row_loss)
{
    const int row = blockIdx.x;
    const int t   = threadIdx.x;      // 256
    const int lab = labels[row];

    // target logit from the SAME fp8 values the GEMM consumed (consistent cancellation)
    const uint8_t* frow = fb + (size_t)row * DIM;
    const uint8_t* wrow = wb + (size_t)lab * DIM;
    uint32_t fa = *reinterpret_cast<const uint16_t*>(frow + 2 * t);
    uint32_t wa = *reinterpret_cast<const uint16_t*>(wrow + 2 * t);
    float d = fp82f(fa & 0xffu) * fp82f(wa & 0xffu)
            + fp82f(fa >> 8)    * fp82f(wa >> 8);
    #pragma unroll
    for (int k = 1; k < 64; k <<= 1) d += __shfl_xor(d, k);

    float s = 0.0f;
    for (int i = t; i < NT; i += 256) s += ps[(size_t)i * B_ROWS + row];
    #pragma unroll
    for (int k = 1; k < 64; k <<= 1) s += __shfl_xor(s, k);

    __shared__ float sd[4], ssm[4];
    if ((t & 63) == 0) { sd[t >> 6] = d; ssm[t >> 6] = s; }
    __syncthreads();
    if (t == 0) {
        const float dt = sd[0] + sd[1] + sd[2] + sd[3];
        float S = ssm[0] + ssm[1] + ssm[2] + ssm[3];
        const float lt = 64.0f * dt;
        // swap unmargined target term for margined one; remove pad columns (logit 0)
        S += expf(lt - 96.0f) - expf(lt - 64.0f) - (float)NPAD * expf(-64.0f);
        row_loss[row] = 64.0f + logf(S) - (lt - 32.0f);
    }
}

// ---------- pass 4: mean over rows
__global__ __launch_bounds__(256) void mean_k(const float* __restrict__ rl, float* __restrict__ out)
{
    const int t = threadIdx.x;
    float s = 0.0f;
    for (int i = t; i < B_ROWS; i += 256) s += rl[i];
    #pragma unroll
    for (int k = 1; k < 64; k <<= 1) s += __shfl_xor(s, k);
    __shared__ float r4[4];
    if ((t & 63) == 0) r4[t >> 6] = s;
    __syncthreads();
    if (t == 0) out[0] = (r4[0] + r4[1] + r4[2] + r4[3]) * (1.0f / B_ROWS);
}

extern "C" void kernel_launch(void* const* d_in, const int* in_sizes, int n_in,
                              void* d_out, int out_size, void* d_ws, size_t ws_size,
                              hipStream_t stream)
{
    const float* features = (const float*)d_in[0];
    const int*   labels   = (const int*)d_in[1];
    const float* weight   = (const float*)d_in[2];

    char* ws = (char*)d_ws;
    uint8_t* wb = (uint8_t*)ws;                                          // C_PAD * DIM fp8
    uint8_t* fb = (uint8_t*)(ws + (size_t)C_PAD * DIM);                  // B_ROWS * DIM fp8
    float*   psum = (float*)(ws + (size_t)C_PAD * DIM + (size_t)B_ROWS * DIM);
    float*   rl = psum + (size_t)NT * B_ROWS;

    normalize_rows<<<C_PAD / 4, 256, 0, stream>>>(weight, wb, C_CLS, C_PAD);
    normalize_rows<<<B_ROWS / 4, 256, 0, stream>>>(features, fb, B_ROWS, B_ROWS);
    gemm_lse<<<NT * MT, 256, 0, stream>>>(fb, wb, psum);
    finalize<<<B_ROWS, 256, 0, stream>>>(psum, fb, wb, labels, rl);
    mean_k<<<1, 256, 0, stream>>>(rl, (float*)d_out);
}

// Round 14
// 129.278 us; speedup vs baseline: 1.6631x; 1.0578x over previous
//
#include <hip/hip_runtime.h>
#include <hip/hip_bf16.h>
#include <hip/hip_fp8.h>
#include <stdint.h>

#define B_ROWS 1024
#define DIM    512
#define C_CLS  100000
#define C_PAD  100352          // 8 XCDs * 98 ntiles * 128
#define NT     784             // C_PAD / 128
#define NT_PER_XCD 98
#define MT     8               // B_ROWS / 128
#define NPAD   (C_PAD - C_CLS) // 352 pad cols, logit 0

using f32x4 = __attribute__((ext_vector_type(4))) float;
using i32x4 = __attribute__((ext_vector_type(4))) int;
using i32x8 = __attribute__((ext_vector_type(8))) int;

#define AS1(p) ((const __attribute__((address_space(1))) uint32_t*)(p))
#define AS3(p) ((__attribute__((address_space(3))) uint32_t*)(p))
#define SBAR()   __builtin_amdgcn_s_barrier()
#define VMCNT0() asm volatile("s_waitcnt vmcnt(0)" ::: "memory")

static __device__ __forceinline__ uint32_t f2fp8(float f) {
    __hip_fp8_e4m3 q(f);
    return (uint32_t)q.__x;
}
static __device__ __forceinline__ float fp82f(uint32_t b) {
    __hip_fp8_e4m3 h;
    h.__x = (__hip_fp8_storage_t)b;
    return (float)h;
}

// ---------- pass 1: per-row L2 normalize (one wave per row), f32 -> fp8 e4m3; pad rows zeroed
__global__ __launch_bounds__(256) void normalize_rows(
    const float* __restrict__ src, uint8_t* __restrict__ dst, int nvalid, int ntotal)
{
    const int row  = blockIdx.x * 4 + (threadIdx.x >> 6);
    const int lane = threadIdx.x & 63;
    if (row >= ntotal) return;
    uint2* d2 = reinterpret_cast<uint2*>(dst + (size_t)row * DIM);    // 8 B per lane
    if (row >= nvalid) { d2[lane] = make_uint2(0u, 0u); return; }
    const float4* s4 = reinterpret_cast<const float4*>(src + (size_t)row * DIM);
    const float4 a = s4[lane * 2], b = s4[lane * 2 + 1];
    float ss = a.x*a.x + a.y*a.y + a.z*a.z + a.w*a.w
             + b.x*b.x + b.y*b.y + b.z*b.z + b.w*b.w;
    #pragma unroll
    for (int k = 1; k < 64; k <<= 1) ss += __shfl_xor(ss, k);
    const float inv = 1.0f / fmaxf(sqrtf(ss), 1e-12f);
    uint2 o;
    o.x = f2fp8(a.x*inv) | (f2fp8(a.y*inv) << 8) | (f2fp8(a.z*inv) << 16) | (f2fp8(a.w*inv) << 24);
    o.y = f2fp8(b.x*inv) | (f2fp8(b.y*inv) << 8) | (f2fp8(b.z*inv) << 16) | (f2fp8(b.w*inv) << 24);
    d2[lane] = o;
}

// ---------- pass 2: 128x128 MX-fp8 MFMA (K=128, unit E8M0 scales -> exact fp8 math at 2x rate),
//            m97 structure: 4 waves, single 32KiB LDS buffer, high TLP.
__global__ __launch_bounds__(256, 3) void gemm_lse(
    const uint8_t* __restrict__ A,    // [B_ROWS][DIM]  fp8
    const uint8_t* __restrict__ W,    // [C_PAD][DIM]   fp8 (pad rows zero)
    float* __restrict__ ps)           // [NT][B_ROWS]
{
    // [region: 0=A, 1=B][128 rows * 128 k fp8 = 16384 B], 32 KiB single buffer
    __shared__ __align__(16) uint8_t lds[2][128 * 128];

    const int tid  = threadIdx.x;
    const int lane = tid & 63;
    const int wid  = tid >> 6;       // 4 waves, 2x2: each owns 64x64
    const int wm   = wid >> 1;
    const int wn   = wid & 1;

    const int b     = blockIdx.x;
    const int xcd   = b & 7;
    const int j     = b >> 3;        // 0..783 within XCD
    const int ntile = xcd * NT_PER_XCD + (j >> 3);
    const int mtile = j & 7;

    const uint8_t* Abase = A + (size_t)mtile * 128 * DIM;
    const uint8_t* Bbase = W + (size_t)ntile * 128 * DIM;

    // staging: per region 1024 16B units (row = u>>3, 16B-sub = u&7); source sub
    // pre-swizzled by row&7 (both-sides XOR, 16B granularity -> contiguous source).
    auto stage = [&](int kt) {
        #pragma unroll
        for (int p = 0; p < 4; ++p) {
            const int u   = tid + p * 256;
            const int row = u >> 3;
            const int sub = (u & 7) ^ (row & 7);
            const uint8_t* As = Abase + (size_t)row * DIM + kt * 128 + sub * 16;
            const uint8_t* Bs = Bbase + (size_t)row * DIM + kt * 128 + sub * 16;
            __builtin_amdgcn_global_load_lds(AS1(As), AS3(&lds[0][u * 16]), 16, 0, 0);
            __builtin_amdgcn_global_load_lds(AS1(Bs), AS3(&lds[1][u * 16]), 16, 0, 0);
        }
    };

    const int l15 = lane & 15;
    const int uhi = lane >> 4;       // k-quarter: lane holds k = uhi*32 .. +32

    i32x8 aF[4], bF[4];
    f32x4 acc[4][4] = {};

    auto ldfrag = [&](const uint8_t* base, int row) -> i32x8 {
        const int swz = row & 7;
        const i32x4 lo = *reinterpret_cast<const i32x4*>(base + row * 128 + (((uhi << 1) | 0) ^ swz) * 16);
        const i32x4 hi = *reinterpret_cast<const i32x4*>(base + row * 128 + (((uhi << 1) | 1) ^ swz) * 16);
        i32x8 r;
        r[0] = lo[0]; r[1] = lo[1]; r[2] = lo[2]; r[3] = lo[3];
        r[4] = hi[0]; r[5] = hi[1]; r[6] = hi[2]; r[7] = hi[3];
        return r;
    };

    // prologue
    stage(0);

    #pragma unroll 1
    for (int kt = 0; kt < 4; ++kt) {
        VMCNT0(); SBAR();                 // tile kt landed for all waves
        #pragma unroll
        for (int mi = 0; mi < 4; ++mi) aF[mi] = ldfrag(&lds[0][0], wm * 64 + mi * 16 + l15);
        #pragma unroll
        for (int ni = 0; ni < 4; ++ni) bF[ni] = ldfrag(&lds[1][0], wn * 64 + ni * 16 + l15);
        #pragma unroll
        for (int mi = 0; mi < 4; ++mi)
            #pragma unroll
            for (int ni = 0; ni < 4; ++ni)
                acc[mi][ni] = __builtin_amdgcn_mfma_scale_f32_16x16x128_f8f6f4(
                    aF[mi], bF[ni], acc[mi][ni], 0, 0, 0, 127, 0, 127);
        SBAR();                           // all waves' reads retired -> overwrite safe
        if (kt < 3) stage(kt + 1);
    }

    // epilogue: logits = 64*cos in [-64,64]; fixed shift 64 -> sum exp(logit-64)
    __syncthreads();                               // full drain; reuse LDS as red buffer
    float* red = reinterpret_cast<float*>(&lds[0][0]);      // [128 rows][2 wn]
    #pragma unroll
    for (int mi = 0; mi < 4; ++mi) {
        #pragma unroll
        for (int r = 0; r < 4; ++r) {
            float s = __expf(fmaf(acc[mi][0][r], 64.0f, -64.0f))
                    + __expf(fmaf(acc[mi][1][r], 64.0f, -64.0f))
                    + __expf(fmaf(acc[mi][2][r], 64.0f, -64.0f))
                    + __expf(fmaf(acc[mi][3][r], 64.0f, -64.0f));
            #pragma unroll
            for (int k = 1; k < 16; k <<= 1) s += __shfl_xor(s, k);
            if (l15 == 0) red[(wm * 64 + mi * 16 + uhi * 4 + r) * 2 + wn] = s;
        }
    }
    __syncthreads();
    if (tid < 128)
        ps[(size_t)ntile * B_ROWS + mtile * 128 + tid] = red[tid * 2] + red[tid * 2 + 1];
}

// ---------- pass 3: per-row sum of partials + exact margin/pad correction
__global__ __launch_bounds__(256) void finalize(
    const float* __restrict__ ps,
    const uint8_t* __restrict__ fb, const uint8_t* __restrict__ wb,
    const int* __restrict__ labels, float* __restrict__ row_loss)
{
    const int row = blockIdx.x;
    const int t   = threadIdx.x;      // 256
    const int lab = labels[row];

    // target logit from the SAME fp8 values the GEMM consumed (consistent cancellation)
    const uint8_t* frow = fb + (size_t)row * DIM;
    const uint8_t* wrow = wb + (size_t)lab * DIM;
    uint32_t fa = *reinterpret_cast<const uint16_t*>(frow + 2 * t);
    uint32_t wa = *reinterpret_cast<const uint16_t*>(wrow + 2 * t);
    float d = fp82f(fa & 0xffu) * fp82f(wa & 0xffu)
            + fp82f(fa >> 8)    * fp82f(wa >> 8);
    #pragma unroll
    for (int k = 1; k < 64; k <<= 1) d += __shfl_xor(d, k);

    float s = 0.0f;
    for (int i = t; i < NT; i += 256) s += ps[(size_t)i * B_ROWS + row];
    #pragma unroll
    for (int k = 1; k < 64; k <<= 1) s += __shfl_xor(s, k);

    __shared__ float sd[4], ssm[4];
    if ((t & 63) == 0) { sd[t >> 6] = d; ssm[t >> 6] = s; }
    __syncthreads();
    if (t == 0) {
        const float dt = sd[0] + sd[1] + sd[2] + sd[3];
        float S = ssm[0] + ssm[1] + ssm[2] + ssm[3];
        const float lt = 64.0f * dt;
        // swap unmargined target term for margined one; remove pad columns (logit 0)
        S += expf(lt - 96.0f) - expf(lt - 64.0f) - (float)NPAD * expf(-64.0f);
        row_loss[row] = 64.0f + logf(S) - (lt - 32.0f);
    }
}

// ---------- pass 4: mean over rows
__global__ __launch_bounds__(256) void mean_k(const float* __restrict__ rl, float* __restrict__ out)
{
    const int t = threadIdx.x;
    float s = 0.0f;
    for (int i = t; i < B_ROWS; i += 256) s += rl[i];
    #pragma unroll
    for (int k = 1; k < 64; k <<= 1) s += __shfl_xor(s, k);
    __shared__ float r4[4];
    if ((t & 63) == 0) r4[t >> 6] = s;
    __syncthreads();
    if (t == 0) out[0] = (r4[0] + r4[1] + r4[2] + r4[3]) * (1.0f / B_ROWS);
}

extern "C" void kernel_launch(void* const* d_in, const int* in_sizes, int n_in,
                              void* d_out, int out_size, void* d_ws, size_t ws_size,
                              hipStream_t stream)
{
    const float* features = (const float*)d_in[0];
    const int*   labels   = (const int*)d_in[1];
    const float* weight   = (const float*)d_in[2];

    char* ws = (char*)d_ws;
    uint8_t* wb = (uint8_t*)ws;                                          // C_PAD * DIM fp8
    uint8_t* fb = (uint8_t*)(ws + (size_t)C_PAD * DIM);                  // B_ROWS * DIM fp8
    float*   psum = (float*)(ws + (size_t)C_PAD * DIM + (size_t)B_ROWS * DIM);
    float*   rl = psum + (size_t)NT * B_ROWS;

    normalize_rows<<<C_PAD / 4, 256, 0, stream>>>(weight, wb, C_CLS, C_PAD);
    normalize_rows<<<B_ROWS / 4, 256, 0, stream>>>(features, fb, B_ROWS, B_ROWS);
    gemm_lse<<<NT * MT, 256, 0, stream>>>(fb, wb, psum);
    finalize<<<B_ROWS, 256, 0, stream>>>(psum, fb, wb, labels, rl);
    mean_k<<<1, 256, 0, stream>>>(rl, (float*)d_out);
}